// Round 15
// baseline (17.393 us; speedup 1.0000x reference)
//
#include <hip/hip_runtime.h>
#include <math.h>

#define NG      1024
#define IMG_H   128
#define IMG_W   128
#define MIN_A   (1.0f / 255.0f)
#define LOG2E   1.4426950408889634f

// SINGLE-DISPATCH fused rasterizer. 256 blocks x 1024 threads, block = one
// 8x8 tile, fully independent blocks (no cross-block sync/fences — the r5/r12
// ~100us coherence failure mode is structurally absent).
//
// Per block:
//  1. thread tid projects gaussian tid (records to LDS by original index),
//     computes its exact alpha>=1/255 AABB, tests vs this tile (register).
//  2. hits compacted via LDS atomic (order arbitrary).
//  3. hits ranked among themselves by (z, original idx) — identical relative
//     order to the global z-sort; skipped gaussians contribute exactly
//     T*=1.0, +0 color, so compositing hits-only in hit-sorted order is
//     bit-equivalent to the reference's full sorted sweep.
//  4. composite: wave w = z-contiguous chunk w of the sorted hit list,
//     lane = pixel; wave-uniform record broadcasts; 16 partials per pixel;
//     16-step front-to-back scan; write image.
__global__ __launch_bounds__(1024) void gs_fused_tile(
    const float* __restrict__ pos, const float* __restrict__ cov,
    const float* __restrict__ col, const float* __restrict__ opa,
    const float* __restrict__ cm, float* __restrict__ out)
{
    __shared__ float  zsh[NG];        //  4 KB  camera z by original idx
    __shared__ float4 s0[NG];         // 16 KB  {mx, my, a2, b2}
    __shared__ float4 s1[NG];         // 16 KB  {c2, op, colR, colG}
    __shared__ float  s2[NG];         //  4 KB  colB
    __shared__ int    hitlist[NG];    //  4 KB  compacted hit ids (unordered)
    __shared__ float2 hzp[NG];        //  8 KB  {z, (float)idx} per hit
    __shared__ int    order[NG];      //  4 KB  sorted hit ids
    __shared__ float4 part[16][64];   //  4 KB  [chunk][pixel]
    __shared__ int    hcnt;

    const int tid  = threadIdx.x;
    const int tile = blockIdx.x;                 // 16x16 tiles
    const float tx0 = (float)((tile & 15) << 3);
    const float ty0 = (float)((tile >> 4) << 3);
    const float txl = tx0 + 0.5f, txh = tx0 + 7.5f;
    const float tyl = ty0 + 0.5f, tyh = ty0 + 7.5f;

    if (tid == 0) hcnt = 0;

    // ---- 1. project gaussian `tid`; records + z to LDS; tile hit test -----
    bool hit;
    {
        const float R00 = cm[0], R01 = cm[1], R02 = cm[2],  T0 = cm[3];
        const float R10 = cm[4], R11 = cm[5], R12 = cm[6],  T1 = cm[7];
        const float R20 = cm[8], R21 = cm[9], R22 = cm[10], T2 = cm[11];

        const float p0 = pos[3*tid], p1 = pos[3*tid+1], p2 = pos[3*tid+2];
        const float x = R00*p0 + R01*p1 + R02*p2 + T0;
        const float y = R10*p0 + R11*p1 + R12*p2 + T1;
        const float z = R20*p0 + R21*p1 + R22*p2 + T2;

        const float focal = 110.85125168440814f;   // 0.5*128/tan(pi/6)
        const float zc = fmaxf(z, 1e-6f);
        const float mx = focal * x / zc + 0.5f * IMG_W;
        const float my = focal * y / zc + 0.5f * IMG_H;

        const float c00 = cov[9*tid+0], c01 = cov[9*tid+1], c02 = cov[9*tid+2];
        const float c10 = cov[9*tid+3], c11 = cov[9*tid+4], c12 = cov[9*tid+5];
        const float c20 = cov[9*tid+6], c21 = cov[9*tid+7], c22 = cov[9*tid+8];
        const float s00 = c00, s01 = 0.5f*(c01+c10), s02 = 0.5f*(c02+c20);
        const float s11 = c11, s12 = 0.5f*(c12+c21), s22 = c22;

        const float RS00 = R00*s00 + R01*s01 + R02*s02;
        const float RS01 = R00*s01 + R01*s11 + R02*s12;
        const float RS02 = R00*s02 + R01*s12 + R02*s22;
        const float RS10 = R10*s00 + R11*s01 + R12*s02;
        const float RS11 = R10*s01 + R11*s11 + R12*s12;
        const float RS12 = R10*s02 + R11*s12 + R12*s22;
        const float RS20 = R20*s00 + R21*s01 + R22*s02;
        const float RS21 = R20*s01 + R21*s11 + R22*s12;
        const float RS22 = R20*s02 + R21*s12 + R22*s22;
        const float CC00 = RS00*R00 + RS01*R01 + RS02*R02;
        const float CC01 = RS00*R10 + RS01*R11 + RS02*R12;
        const float CC02 = RS00*R20 + RS01*R21 + RS02*R22;
        const float CC11 = RS10*R10 + RS11*R11 + RS12*R12;
        const float CC12 = RS10*R20 + RS11*R21 + RS12*R22;
        const float CC20 = RS20*R00 + RS21*R01 + RS22*R02;
        const float CC21 = RS20*R10 + RS21*R11 + RS22*R12;
        const float CC22 = RS20*R20 + RS21*R21 + RS22*R22;

        const float j00 = focal / zc, j02 = -focal * x / (zc*zc);
        const float j11 = focal / zc, j12 = -focal * y / (zc*zc);

        const float v00 = CC00*j00 + CC02*j02;
        const float v02 = CC20*j00 + CC22*j02;
        const float v10 = CC01*j11 + CC02*j12;
        const float v11 = CC11*j11 + CC12*j12;
        const float v12 = CC21*j11 + CC22*j12;

        const float a  = j00*v00 + j02*v02 + 0.3f;
        const float bq = j00*v10 + j02*v12;
        const float cQ = j11*v11 + j12*v12 + 0.3f;

        const float det = a*cQ - bq*bq;
        const float det_safe = (det > 0.f) ? det : 1.f;
        const float conA =  cQ / det_safe;
        const float conB = -bq / det_safe;
        const float conC =  a  / det_safe;

        const bool  valid  = (z > 0.2f) && (det > 0.f);
        const float op_eff = valid ? opa[tid] : 0.f;

        float dxm, dym;
        if (op_eff * 255.f > 1.f) {
            const float sN = logf(255.f * op_eff);
            dxm = sqrtf(2.f * sN * a)  * 1.001f + 0.06f;   // conservative outward
            dym = sqrtf(2.f * sN * cQ) * 1.001f + 0.06f;
        } else {
            dxm = -1e30f; dym = -1e30f;                    // never visible
        }

        zsh[tid] = z;
        s0[tid] = make_float4(mx, my, -0.5f*conA*LOG2E, -conB*LOG2E);
        s1[tid] = make_float4(-0.5f*conC*LOG2E, op_eff, col[3*tid], col[3*tid+1]);
        s2[tid] = col[3*tid+2];

        hit = (mx - dxm <= txh) && (mx + dxm >= txl)
           && (my - dym <= tyh) && (my + dym >= tyl);
    }
    __syncthreads();

    // ---- 2. compact hit ids (order arbitrary; sorted next) ----------------
    if (hit) { const int p = atomicAdd(&hcnt, 1); hitlist[p] = tid; }
    __syncthreads();
    const int H = hcnt;

    for (int k = tid; k < H; k += 1024) {
        const int id = hitlist[k];
        hzp[k] = make_float2(zsh[id], (float)id);   // idx<1024 exact in float
    }
    __syncthreads();

    // ---- 3. rank each hit among hits by (z, idx) -> deterministic order ---
    for (int k = tid; k < H; k += 1024) {
        const float2 me = hzp[k];
        int r = 0;
        for (int j = 0; j < H; ++j) {
            const float2 oz = hzp[j];
            r += (oz.x < me.x || (oz.x == me.x && oz.y < me.y)) ? 1 : 0;
        }
        order[r] = (int)me.y;
    }
    __syncthreads();

    // ---- 4. composite: wave = sorted-hit chunk, lane = pixel --------------
    const int w    = tid >> 6;
    const int lane = tid & 63;
    const float pxf = tx0 + (float)(lane & 7) + 0.5f;
    const float pyf = ty0 + (float)(lane >> 3) + 0.5f;

    const int C  = (H + 15) >> 4;                // chunk size
    const int k0 = w * C;
    const int k1 = (k0 + C < H) ? (k0 + C) : H;

    float T = 1.f, cr = 0.f, cg = 0.f, cb = 0.f;
    for (int k = k0; k < k1; ++k) {
        const int id = order[k];                 // wave-uniform
        const float4 A  = s0[id];                // broadcast reads
        const float4 B  = s1[id];
        const float  Cc = s2[id];
        const float dx = pxf - A.x;
        const float dy = pyf - A.y;
        const float pw = fminf(A.z*dx*dx + B.x*dy*dy + A.w*(dx*dy), 0.f);
        const float G = __builtin_amdgcn_exp2f(pw);
        float alpha = fminf(B.y * G, 0.99f);
        alpha = (alpha >= MIN_A) ? alpha : 0.f;
        const float wT = alpha * T;
        cr = fmaf(wT, B.z, cr);
        cg = fmaf(wT, B.w, cg);
        cb = fmaf(wT, Cc,  cb);
        T *= (1.f - alpha);
    }

    part[w][lane] = make_float4(cr, cg, cb, T);
    __syncthreads();

    if (tid < 64) {                              // per-pixel 16-chunk scan
        float Ts = 1.f, r = 0.f, g = 0.f, b = 0.f;
        #pragma unroll
        for (int k = 0; k < 16; ++k) {
            const float4 v = part[k][tid];
            r = fmaf(Ts, v.x, r);
            g = fmaf(Ts, v.y, g);
            b = fmaf(Ts, v.z, b);
            Ts *= v.w;
        }
        const int px = (int)tx0 + (tid & 7);
        const int py = (int)ty0 + (tid >> 3);
        float* o = out + 3 * (py * IMG_W + px);
        o[0] = r; o[1] = g; o[2] = b;
    }
}

// ---------------------------------------------------------------------------
extern "C" void kernel_launch(void* const* d_in, const int* in_sizes, int n_in,
                              void* d_out, int out_size, void* d_ws, size_t ws_size,
                              hipStream_t stream) {
    const float* pos = (const float*)d_in[0];
    const float* cov = (const float*)d_in[1];
    const float* col = (const float*)d_in[2];
    const float* opa = (const float*)d_in[3];
    const float* cm  = (const float*)d_in[4];

    gs_fused_tile<<<256, 1024, 0, stream>>>(pos, cov, col, opa, cm,
                                            (float*)d_out);
}

// Round 16
// 13.109 us; speedup vs baseline: 1.3268x; 1.3268x over previous
//
#include <hip/hip_runtime.h>
#include <math.h>

#define NG      1024
#define IMG_H   128
#define IMG_W   128
#define NPIX    (IMG_H * IMG_W)
#define MIN_A   (1.0f / 255.0f)
#define LOG2E   1.4426950408889634f

// Record layout (per gaussian, sorted by z):
//  g0 = {mx, my, a2, b2}          a2 = -0.5*conicA*log2e, b2 = -conicB*log2e
//  g1 = {c2, op_eff, colR, colG}  c2 = -0.5*conicC*log2e
//  g2 = colB
//  g3 = {mx, my, dxm, dym}        exact AABB of the alpha>=1/255 level set
// G = exp2( min(a2*dx^2 + c2*dy^2 + b2*dx*dy, 0) )

// ---------------------------------------------------------------------------
// Kernel 1: fused project + stable rank-sort + scatter. 64 blocks x 1024.
// Block owns 16 gaussians. z one-per-thread from direct coalesced pos loads;
// rank distributed 64-way (thread (g=tid&15, q=tid>>4) counts z-chunk
// [16q,16q+16) = 4 b128 reads); threads 0..15 sum partials, project their
// gaussian from direct global loads, scatter by rank.
// ---------------------------------------------------------------------------
__global__ __launch_bounds__(1024) void gs_prep(
    const float* __restrict__ pos, const float* __restrict__ cov,
    const float* __restrict__ col, const float* __restrict__ opa,
    const float* __restrict__ cm,
    float4* __restrict__ g0, float4* __restrict__ g1, float* __restrict__ g2,
    float4* __restrict__ g3)
{
    __shared__ float zsh[NG];            // 4 KB
    __shared__ int   prank[64][16];      // 4 KB [q][g]

    const int tid = threadIdx.x;
    const int b   = blockIdx.x;          // 64 blocks, 16 gaussians each

    // ---- z for gaussian `tid` from own coalesced pos load -----------------
    const float R20 = cm[8], R21 = cm[9], R22 = cm[10], T2 = cm[11];
    {
        const float p0 = pos[3*tid], p1 = pos[3*tid+1], p2 = pos[3*tid+2];
        zsh[tid] = fmaf(R20, p0, fmaf(R21, p1, fmaf(R22, p2, T2)));
    }
    __syncthreads();

    // ---- distributed stable rank (64-way: 4 b128 reads per thread) --------
    {
        const int g = tid & 15, q = tid >> 4;
        const int i = (b << 4) + g;
        const float zi = zsh[i];
        const float4* z4 = (const float4*)zsh;
        int r = 0;
        #pragma unroll
        for (int j4 = q * 4; j4 < q * 4 + 4; ++j4) {
            const float4 v = z4[j4];
            const int j = 4 * j4;
            r += (v.x < zi || (v.x == zi && j + 0 < i)) ? 1 : 0;
            r += (v.y < zi || (v.y == zi && j + 1 < i)) ? 1 : 0;
            r += (v.z < zi || (v.z == zi && j + 2 < i)) ? 1 : 0;
            r += (v.w < zi || (v.w == zi && j + 3 < i)) ? 1 : 0;
        }
        prank[q][g] = r;
    }
    __syncthreads();

    // ---- threads 0..15: sum rank, project, scatter ------------------------
    if (tid < 16) {
        const int g = tid;
        const int i = (b << 4) + g;

        int rank = 0;
        #pragma unroll
        for (int q = 0; q < 64; ++q) rank += prank[q][g];

        const float R00 = cm[0], R01 = cm[1], R02 = cm[2],  T0 = cm[3];
        const float R10 = cm[4], R11 = cm[5], R12 = cm[6],  T1 = cm[7];

        const float p0 = pos[3*i], p1 = pos[3*i+1], p2 = pos[3*i+2];
        const float x = R00*p0 + R01*p1 + R02*p2 + T0;
        const float y = R10*p0 + R11*p1 + R12*p2 + T1;
        const float z = zsh[i];

        const float focal = 110.85125168440814f;   // 0.5*128/tan(pi/6)
        const float zc = fmaxf(z, 1e-6f);
        const float mx = focal * x / zc + 0.5f * IMG_W;
        const float my = focal * y / zc + 0.5f * IMG_H;

        const float c00 = cov[9*i+0], c01 = cov[9*i+1], c02 = cov[9*i+2];
        const float c10 = cov[9*i+3], c11 = cov[9*i+4], c12 = cov[9*i+5];
        const float c20 = cov[9*i+6], c21 = cov[9*i+7], c22 = cov[9*i+8];
        const float s00 = c00, s01 = 0.5f*(c01+c10), s02 = 0.5f*(c02+c20);
        const float s11 = c11, s12 = 0.5f*(c12+c21), s22 = c22;

        const float RS00 = R00*s00 + R01*s01 + R02*s02;
        const float RS01 = R00*s01 + R01*s11 + R02*s12;
        const float RS02 = R00*s02 + R01*s12 + R02*s22;
        const float RS10 = R10*s00 + R11*s01 + R12*s02;
        const float RS11 = R10*s01 + R11*s11 + R12*s12;
        const float RS12 = R10*s02 + R11*s12 + R12*s22;
        const float RS20 = R20*s00 + R21*s01 + R22*s02;
        const float RS21 = R20*s01 + R21*s11 + R22*s12;
        const float RS22 = R20*s02 + R21*s12 + R22*s22;
        const float CC00 = RS00*R00 + RS01*R01 + RS02*R02;
        const float CC01 = RS00*R10 + RS01*R11 + RS02*R12;
        const float CC02 = RS00*R20 + RS01*R21 + RS02*R22;
        const float CC11 = RS10*R10 + RS11*R11 + RS12*R12;
        const float CC12 = RS10*R20 + RS11*R21 + RS12*R22;
        const float CC20 = RS20*R00 + RS21*R01 + RS22*R02;
        const float CC21 = RS20*R10 + RS21*R11 + RS22*R12;
        const float CC22 = RS20*R20 + RS21*R21 + RS22*R22;

        const float j00 = focal / zc, j02 = -focal * x / (zc*zc);
        const float j11 = focal / zc, j12 = -focal * y / (zc*zc);

        const float v00 = CC00*j00 + CC02*j02;
        const float v02 = CC20*j00 + CC22*j02;
        const float v10 = CC01*j11 + CC02*j12;
        const float v11 = CC11*j11 + CC12*j12;
        const float v12 = CC21*j11 + CC22*j12;

        const float a  = j00*v00 + j02*v02 + 0.3f;
        const float bq = j00*v10 + j02*v12;
        const float cQ = j11*v11 + j12*v12 + 0.3f;

        const float det = a*cQ - bq*bq;
        const float det_safe = (det > 0.f) ? det : 1.f;
        const float conA =  cQ / det_safe;
        const float conB = -bq / det_safe;
        const float conC =  a  / det_safe;

        const bool  valid  = (z > 0.2f) && (det > 0.f);
        const float op_eff = valid ? opa[i] : 0.f;

        float dxm, dym;
        if (op_eff * 255.f > 1.f) {
            const float sN = logf(255.f * op_eff);
            dxm = sqrtf(2.f * sN * a)  * 1.001f + 0.06f;   // conservative outward
            dym = sqrtf(2.f * sN * cQ) * 1.001f + 0.06f;
        } else {
            dxm = -1e30f; dym = -1e30f;                    // never visible
        }

        g0[rank] = make_float4(mx, my, -0.5f*conA*LOG2E, -conB*LOG2E);
        g1[rank] = make_float4(-0.5f*conC*LOG2E, op_eff, col[3*i], col[3*i+1]);
        g2[rank] = col[3*i+2];
        g3[rank] = make_float4(mx, my, dxm, dym);
    }
}

// ---------------------------------------------------------------------------
// Kernel 2: LDS-resident tile raster, register-cull, fused combine.
// 256 blocks x 1024 threads, 1 block/CU. Block = one 8x8 tile; wave w owns
// sorted chunk [64w, 64w+64). Cull record g3[tid] loaded coalesced into a
// register (wave w's lanes hold exactly its chunk) -> AABB test + __ballot.
// Composite via wave-uniform LDS broadcasts, ascending bit order == z order.
// 16 partials/pixel in LDS; 16-step scan fuses the combine.
// ---------------------------------------------------------------------------
__global__ __launch_bounds__(1024) void gs_raster_tile(
    const float4* __restrict__ g0, const float4* __restrict__ g1,
    const float*  __restrict__ g2, const float4* __restrict__ g3,
    float* __restrict__ out)
{
    __shared__ float4 s0[NG];            // 16 KB
    __shared__ float4 s1[NG];            // 16 KB
    __shared__ float  s2[NG];            //  4 KB
    __shared__ float4 part[16][64];      //  4 KB [chunk][pixel]

    const int tid = threadIdx.x;
    const float4 cl = g3[tid];           // coalesced; wave w lane l = gaussian 64w+l
    s0[tid] = g0[tid];
    s1[tid] = g1[tid];
    s2[tid] = g2[tid];

    const int w    = tid >> 6;           // wave = chunk 0..15
    const int lane = tid & 63;           // pixel in 8x8 tile / cull lane
    const int tile = blockIdx.x;         // 16x16 tiles
    const float tx0 = (float)((tile & 15) << 3);
    const float ty0 = (float)((tile >> 4) << 3);

    const float pxf = tx0 + (float)(lane & 7) + 0.5f;
    const float pyf = ty0 + (float)(lane >> 3) + 0.5f;
    const float txl = tx0 + 0.5f, txh = tx0 + 7.5f;
    const float tyl = ty0 + 0.5f, tyh = ty0 + 7.5f;

    // register cull -> uniform 64-bit mask (no LDS dependency)
    const bool hit = (cl.x - cl.z <= txh) && (cl.x + cl.z >= txl)
                  && (cl.y - cl.w <= tyh) && (cl.y + cl.w >= tyl);
    unsigned long long m = __ballot(hit);

    __syncthreads();                     // s0/s1/s2 ready

    const int base = w * 64;
    float T = 1.f, cr = 0.f, cg = 0.f, cb = 0.f;

    while (m) {                          // ascending bit order == z order
        const int i = __builtin_ctzll(m);
        m &= m - 1;
        const float4 A = s0[base + i];   // wave-uniform broadcasts
        const float4 B = s1[base + i];
        const float  C = s2[base + i];
        const float dx = pxf - A.x;
        const float dy = pyf - A.y;
        const float pw = fminf(A.z*dx*dx + B.x*dy*dy + A.w*(dx*dy), 0.f);
        const float G = __builtin_amdgcn_exp2f(pw);
        float alpha = fminf(B.y * G, 0.99f);
        alpha = (alpha >= MIN_A) ? alpha : 0.f;
        const float wT = alpha * T;
        cr = fmaf(wT, B.z, cr);
        cg = fmaf(wT, B.w, cg);
        cb = fmaf(wT, C,   cb);
        T *= (1.f - alpha);
    }

    part[w][lane] = make_float4(cr, cg, cb, T);
    __syncthreads();

    if (tid < 64) {                      // one thread per pixel: 16-chunk scan
        float Ts = 1.f, r = 0.f, g = 0.f, b = 0.f;
        #pragma unroll
        for (int k = 0; k < 16; ++k) {
            const float4 v = part[k][tid];
            r = fmaf(Ts, v.x, r);
            g = fmaf(Ts, v.y, g);
            b = fmaf(Ts, v.z, b);
            Ts *= v.w;
        }
        const int px = (int)tx0 + (tid & 7);
        const int py = (int)ty0 + (tid >> 3);
        float* o = out + 3 * (py * IMG_W + px);
        o[0] = r; o[1] = g; o[2] = b;
    }
}

// ---------------------------------------------------------------------------
extern "C" void kernel_launch(void* const* d_in, const int* in_sizes, int n_in,
                              void* d_out, int out_size, void* d_ws, size_t ws_size,
                              hipStream_t stream) {
    const float* pos = (const float*)d_in[0];
    const float* cov = (const float*)d_in[1];
    const float* col = (const float*)d_in[2];
    const float* opa = (const float*)d_in[3];
    const float* cm  = (const float*)d_in[4];

    char* ws = (char*)d_ws;
    float4* g0 = (float4*)(ws);                 // 16384 B
    float4* g1 = (float4*)(ws + 16384);         // 16384 B
    float*  g2 = (float*) (ws + 32768);         //  4096 B
    float4* g3 = (float4*)(ws + 36864);         // 16384 B

    gs_prep<<<64, 1024, 0, stream>>>(pos, cov, col, opa, cm, g0, g1, g2, g3);
    gs_raster_tile<<<256, 1024, 0, stream>>>(g0, g1, g2, g3, (float*)d_out);
}